// Round 10
// baseline (336.593 us; speedup 1.0000x reference)
//
#include <hip/hip_runtime.h>
#include <hip/hip_cooperative_groups.h>
#include <cstdint>
#include <cstddef>

namespace cg = cooperative_groups;

#define B_  16
#define N_  512
#define D_  256
#define H_  8
#define DK_ 32
// Round 18: cooperative mega-kernel (prep -> QKV GEMM -> attn) with
// grid.sync() between phases. Motivation: rounds 13-17 proved per-kernel
// edits are +-2us and invisible (poison fills mask top-5); fixed overhead
// ~75us (r1/r3 accounting); 2 dispatch drains + gaps are deletable; and a
// single >41us kernel restores counter visibility. Phase math is verbatim
// from the proven r15 kernels; GEMM re-mapped to 8-wave blocks.
// Fallback: if hipLaunchCooperativeKernel fails, launch the 3-dispatch path.

#define QKV_ELEMS 2097152   // B*N*D

__device__ __align__(16) unsigned short g_Qb[QKV_ELEMS];   // [B,H,N,DK] bf16 (pre-scaled)
__device__ __align__(16) unsigned short g_Kb[QKV_ELEMS];   // [B,H,N,DK] bf16
__device__ __align__(16) unsigned short g_VT[QKV_ELEMS];   // [B,H,tokblk,DK,tok32] bf16
__device__ __align__(16) unsigned short g_Ain[3*QKV_ELEMS];// q/k/v inputs bf16
__device__ __align__(16) unsigned short g_WqB[D_*D_];      // Wq bf16 [n][k]
__device__ __align__(16) unsigned short g_WkB[D_*D_];      // Wk bf16 [n][k]
__device__ __align__(16) unsigned short g_WvB[D_*D_];      // Wv bf16 [n][k]
__device__ __align__(16) unsigned short g_WoB[D_*D_];      // Wo bf16 [k>>5][n][k&31]
__device__ __align__(16) unsigned short g_ST[B_*N_*N_];    // blended dist/adj bf16 [b][q][k]

typedef short v8s __attribute__((ext_vector_type(8)));
typedef float v4f __attribute__((ext_vector_type(4)));

// 1/sqrt(32) * log2(e): Q pre-scale so attn uses exp2 directly
#define QSCALE 0.25503485917270874f

__device__ __forceinline__ unsigned short f2b(float f){
  unsigned int x;
  __builtin_memcpy(&x, &f, 4);
  x = x + 0x7FFFu + ((x >> 16) & 1u);   // round-to-nearest-even
  return (unsigned short)(x >> 16);
}
__device__ __forceinline__ v8s pack8(const float4 a, const float4 b){
  v8s o;
  o[0]=(short)f2b(a.x); o[1]=(short)f2b(a.y); o[2]=(short)f2b(a.z); o[3]=(short)f2b(a.w);
  o[4]=(short)f2b(b.x); o[5]=(short)f2b(b.y); o[6]=(short)f2b(b.z); o[7]=(short)f2b(b.w);
  return o;
}

// ---------------------------------------------------------------------------
// Phase 0: ST build (one (b,qt) per block) + A->bf16 + W->bf16. No LDS.
// ---------------------------------------------------------------------------
__device__ __forceinline__ void phase_prep(
    int bid, int t,
    const float* dist, const float* adjm, const int* mask,
    const float* query, const float* key_, const float* value,
    const float* Wq, const float* Wk, const float* Wv, const float* Wo)
{
  // ---- ST build: (b,qt)=(bid&15,bid>>4), 16 rows x 512 k ----
  {
    const int b = bid & 15, qt = bid >> 4;
    const int row = t >> 5, seg = t & 31;
    const size_t roff = ((size_t)(b*N_ + qt*16 + row))*N_ + seg*16;
    const float* dp = dist + roff;
    const float* ap = adjm + roff;
    const int*   mp = mask + b*N_ + seg*16;
    const float4 d0 = reinterpret_cast<const float4*>(dp)[0];
    const float4 d1 = reinterpret_cast<const float4*>(dp)[1];
    const float4 d2 = reinterpret_cast<const float4*>(dp)[2];
    const float4 d3 = reinterpret_cast<const float4*>(dp)[3];
    const float4 a0 = reinterpret_cast<const float4*>(ap)[0];
    const float4 a1 = reinterpret_cast<const float4*>(ap)[1];
    const float4 a2 = reinterpret_cast<const float4*>(ap)[2];
    const float4 a3 = reinterpret_cast<const float4*>(ap)[3];
    const int4   m0 = reinterpret_cast<const int4*>(mp)[0];
    const int4   m1 = reinterpret_cast<const int4*>(mp)[1];
    const int4   m2 = reinterpret_cast<const int4*>(mp)[2];
    const int4   m3 = reinterpret_cast<const int4*>(mp)[3];

    float ev[16], av[16];
    #define ST_STEP(i, d4, a4, m4) \
      ev[i+0] = m4.x ? __expf(-d4.x) : 0.f;  av[i+0] = a4.x; \
      ev[i+1] = m4.y ? __expf(-d4.y) : 0.f;  av[i+1] = a4.y; \
      ev[i+2] = m4.z ? __expf(-d4.z) : 0.f;  av[i+2] = a4.z; \
      ev[i+3] = m4.w ? __expf(-d4.w) : 0.f;  av[i+3] = a4.w;
    ST_STEP(0,  d0, a0, m0)
    ST_STEP(4,  d1, a1, m1)
    ST_STEP(8,  d2, a2, m2)
    ST_STEP(12, d3, a3, m3)
    #undef ST_STEP
    float lz = 0.f, la = 0.f;
    #pragma unroll
    for (int i = 0; i < 16; ++i){ lz += ev[i]; la += av[i]; }
    #pragma unroll
    for (int o = 1; o < 32; o <<= 1){   // 32 lanes share a row (lane bits 0..4)
      lz += __shfl_xor(lz, o, 64);
      la += __shfl_xor(la, o, 64);
    }
    const float c0 = (lz > 0.f) ? 0.3f / lz : 0.f;
    const float c1 = 0.4f / (la + 1e-6f);
    v8s s0v, s1v;
    #pragma unroll
    for (int i = 0; i < 8; ++i){
      s0v[i] = (short)f2b(ev[i]*c0   + av[i]*c1);
      s1v[i] = (short)f2b(ev[8+i]*c0 + av[8+i]*c1);
    }
    *reinterpret_cast<v8s*>(g_ST + roff)     = s0v;
    *reinterpret_cast<v8s*>(g_ST + roff + 8) = s1v;
  }

  // ---- A conversion: tensor u, 8 elems per thread per tensor ----
  {
    const size_t base = ((size_t)(bid*512 + t))*8;
    #pragma unroll
    for (int u = 0; u < 3; ++u){
      const float* src = (u==0)?query:(u==1)?key_:value;
      const float4 x0 = reinterpret_cast<const float4*>(src + base)[0];
      const float4 x1 = reinterpret_cast<const float4*>(src + base)[1];
      *reinterpret_cast<v8s*>(g_Ain + (size_t)u*QKV_ELEMS + base) = pack8(x0, x1);
    }
  }

  // ---- W conversion: gid<65536, 4 elems each ----
  {
    const int gid = bid*512 + t;
    if (gid < 65536){
      const int i = gid*4;
      const int z = i >> 16, lo = i & 65535;
      const float* src = (z==0)?Wq:(z==1)?Wk:(z==2)?Wv:Wo;
      const float4 u = *reinterpret_cast<const float4*>(src + lo);
      ushort4 o4;
      o4.x=f2b(u.x); o4.y=f2b(u.y); o4.z=f2b(u.z); o4.w=f2b(u.w);
      if (z < 3){
        unsigned short* dst = (z==0)?g_WqB:(z==1)?g_WkB:g_WvB;
        *reinterpret_cast<ushort4*>(dst + lo) = o4;
      } else {
        const int n = lo >> 8, k = lo & 255;
        *reinterpret_cast<ushort4*>(g_WoB + ((size_t)(k >> 5))*8192 + (size_t)n*32 + (k & 31)) = o4;
      }
    }
  }
}

// ---------------------------------------------------------------------------
// Phase 1: one 64m x 64n GEMM tile, 8 waves (wave = (msub, nhalf)).
// C[m][n] = sum_k A[m][k]*W[n][k] + b[n]. z==2 swapped -> D[n][tok].
// ---------------------------------------------------------------------------
__device__ __forceinline__ void phase_gemm_tile(
    int tile, int t, unsigned short* Wl,
    const float* bq, const float* bk, const float* bv)
{
  const int z  = tile >> 9;                // 0:Q 1:K 2:V
  const int rr = tile & 511;
  const int mt = rr >> 2, nt = rr & 3;     // nt fastest: consecutive share A
  const unsigned short* Ap = g_Ain + (size_t)z*QKV_ELEMS;
  const unsigned short* WB = (z==0) ? g_WqB : (z==1) ? g_WkB : g_WvB;
  const float* bp = (z==0) ? bq : (z==1) ? bk : bv;
  const int w = t >> 6, lane = t & 63, kl = lane & 15, quad = lane >> 4;
  const int msub = w & 3, nhalf = w >> 2;
  const int m0 = mt*64 + msub*16;
  const int nbase = nt*64 + nhalf*32;

  {   // stage bf16 W tile [nt*64 .. +63][0..255]: 512 thr x 32 shorts
    const int row = t >> 3;
    const int ks  = (t & 7) * 32;
    const unsigned short* src = WB + (size_t)(nt*64 + row)*256 + ks;
    unsigned short* dst = Wl + row*264 + ks;
    #pragma unroll
    for (int u = 0; u < 4; ++u)
      *reinterpret_cast<v8s*>(dst + u*8) = *reinterpret_cast<const v8s*>(src + u*8);
  }
  __syncthreads();

  v4f acc[2];
  acc[0] = (v4f){0.f,0.f,0.f,0.f};
  acc[1] = (v4f){0.f,0.f,0.f,0.f};
  const int arow = m0 + kl;

  if (z == 2){
    #pragma unroll
    for (int k0 = 0; k0 < 256; k0 += 32){
      const v8s af = *reinterpret_cast<const v8s*>(Ap + (size_t)arow*256 + k0 + quad*8);
      #pragma unroll
      for (int nb = 0; nb < 2; ++nb){
        const v8s wf = *reinterpret_cast<const v8s*>(&Wl[(nhalf*32 + nb*16 + kl)*264 + k0 + quad*8]);
        acc[nb] = __builtin_amdgcn_mfma_f32_16x16x32_bf16(wf, af, acc[nb], 0, 0, 0);
      }
    }
    // D[n][tok]; tile-interleaved store: [bb,h, tokblk, dk, tok&31]
    const int tok = m0 + kl, bb = tok >> 9, nr = tok & 511;
    #pragma unroll
    for (int nb = 0; nb < 2; ++nb)
      #pragma unroll
      for (int r = 0; r < 4; ++r){
        const int n = nbase + nb*16 + quad*4 + r;
        const float v = acc[nb][r] + bp[n];
        g_VT[(((size_t)bb*H_ + (n>>5))*16 + (nr>>5))*1024 + (size_t)(n&31)*32 + (nr&31)] = f2b(v);
      }
  } else {
    #pragma unroll
    for (int k0 = 0; k0 < 256; k0 += 32){
      const v8s af = *reinterpret_cast<const v8s*>(Ap + (size_t)arow*256 + k0 + quad*8);
      #pragma unroll
      for (int nb = 0; nb < 2; ++nb){
        const v8s wf = *reinterpret_cast<const v8s*>(&Wl[(nhalf*32 + nb*16 + kl)*264 + k0 + quad*8]);
        acc[nb] = __builtin_amdgcn_mfma_f32_16x16x32_bf16(af, wf, acc[nb], 0, 0, 0);
      }
    }
    unsigned short* dst = z ? g_Kb : g_Qb;
    const float sc = (z == 0) ? QSCALE : 1.0f;   // fold 1/sqrt(dk)*log2e into Q
    #pragma unroll
    for (int nb = 0; nb < 2; ++nb){
      const int n = nbase + nb*16 + kl;
      const float bias = bp[n];
      #pragma unroll
      for (int r = 0; r < 4; ++r){
        const int m = m0 + quad*4 + r;
        const float v = (acc[nb][r] + bias) * sc;
        dst[(((size_t)(m>>9)*H_ + (n>>5))*N_ + (m&511))*DK_ + (n&31)] = f2b(v);
      }
    }
  }
  __syncthreads();   // protect Wl for next tile
}

// ---------------------------------------------------------------------------
// Phase 2: attention (r15/best version: 128-key chunks, av[8] prefetch,
// in-register P transpose). STl/Xl alias the W LDS buffer.
// ---------------------------------------------------------------------------
__device__ __forceinline__ void phase_attn(
    int bid, int t, unsigned short* STl, unsigned short* Xl,
    const int* mask, const float* bo, float* out)
{
  const int b  = bid & 15;
  const int qt = bid >> 4;
  const int q0 = qt*16;
  const int w  = t >> 6, lane = t & 63;
  const int kl = lane & 15, quad = lane >> 4;

  // ---- stage precomputed ST tile into padded LDS ----
  {
    const int row = t >> 5;                 // 16 rows, 32 thr each
    const int c16 = (t & 31) * 16;
    const unsigned short* src = g_ST + ((size_t)(b*N_ + q0 + row))*N_ + c16;
    *reinterpret_cast<v8s*>(&STl[row*520 + c16])     = *reinterpret_cast<const v8s*>(src);
    *reinterpret_cast<v8s*>(&STl[row*520 + c16 + 8]) = *reinterpret_cast<const v8s*>(src + 8);
  }

  const int h = w;
  const size_t bh = (size_t)b*H_ + h;
  const unsigned short* Qp = g_Qb + (bh*N_ + q0)*DK_;
  const unsigned short* Kp = g_Kb + bh*N_*DK_;
  const unsigned short* Vp = g_VT + bh*(size_t)(N_*DK_);
  const int* mrow = mask + b*N_;
  const v8s aq = *reinterpret_cast<const v8s*>(Qp + (size_t)kl*DK_ + quad*8);
  const v4f vz = {0.f, 0.f, 0.f, 0.f};

  const int s0 = ((quad & 1) << 5) + kl;
  const int s1 = s0 + 16;
  const int hi = quad >> 1;

  v4f oA0 = vz, oA1 = vz;
  v4f oS0 = vz, oS1 = vz;
  float lsum = 0.f;

  __syncthreads();            // STl visible to all waves

  #pragma unroll 1
  for (int ch = 0; ch < 4; ++ch){
    const int k0 = ch*128;
    v4f acc[8];
    #pragma unroll
    for (int kb = 0; kb < 8; ++kb){
      const v8s bk = *reinterpret_cast<const v8s*>(Kp + (size_t)(k0 + kb*16 + kl)*DK_ + quad*8);
      acc[kb] = __builtin_amdgcn_mfma_f32_16x16x32_bf16(bk, aq, vz, 0, 0, 0);
    }
    v8s av[8];
    #pragma unroll
    for (int cc = 0; cc < 4; ++cc){
      const int kk = k0 + cc*32;
      av[2*cc]   = *reinterpret_cast<const v8s*>(Vp + (size_t)(kk + kl)*32 + quad*8);
      av[2*cc+1] = *reinterpret_cast<const v8s*>(Vp + (size_t)(kk + 16 + kl)*32 + quad*8);
    }
    #pragma unroll
    for (int kb = 0; kb < 8; ++kb){
      const int4 m4 = *reinterpret_cast<const int4*>(mrow + k0 + kb*16 + quad*4);
      const float e0 = m4.x ? __builtin_amdgcn_exp2f(acc[kb][0]) : 0.f;
      const float e1 = m4.y ? __builtin_amdgcn_exp2f(acc[kb][1]) : 0.f;
      const float e2 = m4.z ? __builtin_amdgcn_exp2f(acc[kb][2]) : 0.f;
      const float e3 = m4.w ? __builtin_amdgcn_exp2f(acc[kb][3]) : 0.f;
      acc[kb][0]=e0; acc[kb][1]=e1; acc[kb][2]=e2; acc[kb][3]=e3;
      lsum += e0+e1+e2+e3;
    }
    #pragma unroll
    for (int cc = 0; cc < 4; ++cc){
      const int kk = k0 + cc*32;
      uint32_t pkE0, pkE2, pkO0, pkO2;
      asm("v_cvt_pk_bf16_f32 %0, %1, %2" : "=v"(pkE0) : "v"(acc[2*cc][0]),   "v"(acc[2*cc][1]));
      asm("v_cvt_pk_bf16_f32 %0, %1, %2" : "=v"(pkE2) : "v"(acc[2*cc][2]),   "v"(acc[2*cc][3]));
      asm("v_cvt_pk_bf16_f32 %0, %1, %2" : "=v"(pkO0) : "v"(acc[2*cc+1][0]), "v"(acc[2*cc+1][1]));
      asm("v_cvt_pk_bf16_f32 %0, %1, %2" : "=v"(pkO2) : "v"(acc[2*cc+1][2]), "v"(acc[2*cc+1][3]));
      const uint32_t e0a = (uint32_t)__shfl((int)pkE0, s0, 64);
      const uint32_t o0a = (uint32_t)__shfl((int)pkO0, s0, 64);
      const uint32_t e2a = (uint32_t)__shfl((int)pkE2, s0, 64);
      const uint32_t o2a = (uint32_t)__shfl((int)pkO2, s0, 64);
      const uint32_t e0b = (uint32_t)__shfl((int)pkE0, s1, 64);
      const uint32_t o0b = (uint32_t)__shfl((int)pkO0, s1, 64);
      const uint32_t e2b = (uint32_t)__shfl((int)pkE2, s1, 64);
      const uint32_t o2b = (uint32_t)__shfl((int)pkO2, s1, 64);
      union { v8s v; uint32_t w4[4]; } bp;
      bp.w4[0] = hi ? o0a : e0a;
      bp.w4[1] = hi ? o2a : e2a;
      bp.w4[2] = hi ? o0b : e0b;
      bp.w4[3] = hi ? o2b : e2b;
      const v8s bst = *reinterpret_cast<const v8s*>(&STl[kl*520 + kk + quad*8]);
      oA0 = __builtin_amdgcn_mfma_f32_16x16x32_bf16(av[2*cc],   bp.v, oA0, 0, 0, 0);
      oS0 = __builtin_amdgcn_mfma_f32_16x16x32_bf16(av[2*cc],   bst,  oS0, 0, 0, 0);
      oA1 = __builtin_amdgcn_mfma_f32_16x16x32_bf16(av[2*cc+1], bp.v, oA1, 0, 0, 0);
      oS1 = __builtin_amdgcn_mfma_f32_16x16x32_bf16(av[2*cc+1], bst,  oS1, 0, 0, 0);
    }
  }

  lsum += __shfl_xor(lsum, 16, 64);
  lsum += __shfl_xor(lsum, 32, 64);
  const float inv = (lsum > 0.f) ? 0.3f / lsum : 0.f;

  unsigned short* xr = Xl + kl*272 + h*32;
  #pragma unroll
  for (int r = 0; r < 4; ++r){
    xr[     quad*4 + r] = f2b(oA0[r]*inv + oS0[r]);
    xr[16 + quad*4 + r] = f2b(oA1[r]*inv + oS1[r]);
  }
  __syncthreads();

  {
    const int n0 = w*32;
    v4f a2[2];
    a2[0] = vz; a2[1] = vz;
    #pragma unroll
    for (int k0 = 0; k0 < 256; k0 += 32){
      const v8s af = *reinterpret_cast<const v8s*>(&Xl[kl*272 + k0 + quad*8]);
      #pragma unroll
      for (int nb = 0; nb < 2; ++nb){
        const v8s wf = *reinterpret_cast<const v8s*>(
            g_WoB + (size_t)(k0 >> 5)*8192 + (size_t)(n0 + nb*16 + kl)*32 + quad*8);
        a2[nb] = __builtin_amdgcn_mfma_f32_16x16x32_bf16(af, wf, a2[nb], 0, 0, 0);
      }
    }
    #pragma unroll
    for (int nb = 0; nb < 2; ++nb){
      const int n = n0 + nb*16 + kl;
      const float bias = bo[n];
      #pragma unroll
      for (int r = 0; r < 4; ++r)
        out[((size_t)(b*N_ + q0 + quad*4 + r))*256 + n] = a2[nb][r] + bias;
    }
  }
}

// ---------------------------------------------------------------------------
// Mega-kernel (cooperative): prep -> sync -> 3 GEMM tiles -> sync -> attn.
// ---------------------------------------------------------------------------
__global__ __launch_bounds__(512, 4) void mega(
    const float* __restrict__ dist, const float* __restrict__ adjm,
    const int* __restrict__ mask,
    const float* __restrict__ query, const float* __restrict__ key_,
    const float* __restrict__ value,
    const float* __restrict__ Wq, const float* __restrict__ Wk,
    const float* __restrict__ Wv, const float* __restrict__ Wo,
    const float* __restrict__ bq, const float* __restrict__ bk,
    const float* __restrict__ bv, const float* __restrict__ bo,
    float* __restrict__ out)
{
  __shared__ unsigned short smem[64*264];   // 33.8 KB; aliased by each phase
  const int bid = blockIdx.x;
  const int t   = threadIdx.x;

  phase_prep(bid, t, dist, adjm, mask, query, key_, value, Wq, Wk, Wv, Wo);

  cg::this_grid().sync();

  #pragma unroll 1
  for (int i = 0; i < 3; ++i)
    phase_gemm_tile(bid + i*512, t, smem, bq, bk, bv);

  cg::this_grid().sync();

  phase_attn(bid, t, smem, smem + 16*520, mask, bo, out);
}

// ---------------------------------------------------------------------------
// Fallback 3-dispatch path (same device code, no grid sync).
// ---------------------------------------------------------------------------
__global__ __launch_bounds__(512) void prep_k(
    const float* __restrict__ dist, const float* __restrict__ adjm,
    const int* __restrict__ mask,
    const float* __restrict__ query, const float* __restrict__ key_,
    const float* __restrict__ value,
    const float* __restrict__ Wq, const float* __restrict__ Wk,
    const float* __restrict__ Wv, const float* __restrict__ Wo)
{
  phase_prep(blockIdx.x, threadIdx.x, dist, adjm, mask, query, key_, value,
             Wq, Wk, Wv, Wo);
}

__global__ __launch_bounds__(512, 4) void gemm_k(
    const float* __restrict__ bq, const float* __restrict__ bk,
    const float* __restrict__ bv)
{
  __shared__ unsigned short smem[64*264];
  #pragma unroll 1
  for (int i = 0; i < 3; ++i)
    phase_gemm_tile(blockIdx.x + i*512, threadIdx.x, smem, bq, bk, bv);
}

__global__ __launch_bounds__(512, 4) void attn_k(
    const int* __restrict__ mask, const float* __restrict__ bo,
    float* __restrict__ out)
{
  __shared__ unsigned short smem[16*520 + 16*272];
  phase_attn(blockIdx.x, threadIdx.x, smem, smem + 16*520, mask, bo, out);
}

extern "C" void kernel_launch(void* const* d_in, const int* in_sizes, int n_in,
                              void* d_out, int out_size, void* d_ws, size_t ws_size,
                              hipStream_t stream)
{
  const float* query = (const float*)d_in[0];
  const float* key_  = (const float*)d_in[1];
  const float* value = (const float*)d_in[2];
  const float* adjm  = (const float*)d_in[3];
  const float* dist  = (const float*)d_in[4];
  // d_in[5] = edges_att (unused)
  const int*   mask  = (const int*)d_in[6];
  const float* Wq = (const float*)d_in[7];  const float* bq = (const float*)d_in[8];
  const float* Wk = (const float*)d_in[9];  const float* bk = (const float*)d_in[10];
  const float* Wv = (const float*)d_in[11]; const float* bv = (const float*)d_in[12];
  const float* Wo = (const float*)d_in[13]; const float* bo = (const float*)d_in[14];
  float* out = (float*)d_out;

  void* kargs[] = {
    (void*)&dist, (void*)&adjm, (void*)&mask,
    (void*)&query, (void*)&key_, (void*)&value,
    (void*)&Wq, (void*)&Wk, (void*)&Wv, (void*)&Wo,
    (void*)&bq, (void*)&bk, (void*)&bv, (void*)&bo,
    (void*)&out
  };
  hipError_t err = hipLaunchCooperativeKernel((const void*)mega,
                                              dim3(512), dim3(512),
                                              kargs, 0, stream);
  if (err != hipSuccess){
    // fallback: 3-dispatch path (stream-ordered, no grid sync needed)
    prep_k<<<512, 512, 0, stream>>>(dist, adjm, mask, query, key_, value,
                                    Wq, Wk, Wv, Wo);
    gemm_k<<<512, 512, 0, stream>>>(bq, bk, bv);
    attn_k<<<512, 512, 0, stream>>>(mask, bo, out);
  }
}

// Round 11
// 162.608 us; speedup vs baseline: 2.0700x; 2.0700x over previous
//
#include <hip/hip_runtime.h>
#include <cstdint>
#include <cstddef>

#define B_  16
#define N_  512
#define D_  256
#define H_  8
#define DK_ 32
// Round 19: REVERT to the round-15 build (best measured: 160.27us).
// r16 (+3us), r17 (+1.5us), r18 mega (+176us: compiler allocated 64 VGPR
// for the fused kernel -> attn phase spilled to scratch, +30MB writes) all
// regressed. Three independent failures show hipcc gives multi-role fused
// kernels minimal-register serialized schedules; the factored 3-dispatch
// structure is the proven optimum for this decomposition.
//  1) prep (2816 blk, no LDS): ST build + A fp32->bf16 + W->bf16.
//  2) qkv_gemm (1536 blk x 256 thr): bf16 A + LDS-staged bf16 W, XCD swizzle.
//  3) attn (512 blk x 512 thr): swapped QK^T, in-register P transpose,
//     128-key chunks, av[8] prefetch, deferred softmax normalization.

#define QKV_ELEMS 2097152   // B*N*D

__device__ __align__(16) unsigned short g_Qb[QKV_ELEMS];   // [B,H,N,DK] bf16 (pre-scaled)
__device__ __align__(16) unsigned short g_Kb[QKV_ELEMS];   // [B,H,N,DK] bf16
__device__ __align__(16) unsigned short g_VT[QKV_ELEMS];   // [B,H,tokblk,DK,tok32] bf16
__device__ __align__(16) unsigned short g_Ain[3*QKV_ELEMS];// q/k/v inputs bf16
__device__ __align__(16) unsigned short g_WqB[D_*D_];      // Wq bf16 [n][k]
__device__ __align__(16) unsigned short g_WkB[D_*D_];      // Wk bf16 [n][k]
__device__ __align__(16) unsigned short g_WvB[D_*D_];      // Wv bf16 [n][k]
__device__ __align__(16) unsigned short g_WoB[D_*D_];      // Wo bf16 [k>>5][n][k&31]
__device__ __align__(16) unsigned short g_ST[B_*N_*N_];    // blended dist/adj bf16 [b][q][k]

typedef short v8s __attribute__((ext_vector_type(8)));
typedef float v4f __attribute__((ext_vector_type(4)));

// 1/sqrt(32) * log2(e): Q pre-scale so attn uses exp2 directly
#define QSCALE 0.25503485917270874f

__device__ __forceinline__ unsigned short f2b(float f){
  unsigned int x;
  __builtin_memcpy(&x, &f, 4);
  x = x + 0x7FFFu + ((x >> 16) & 1u);   // round-to-nearest-even
  return (unsigned short)(x >> 16);
}
__device__ __forceinline__ v8s pack8(const float4 a, const float4 b){
  v8s o;
  o[0]=(short)f2b(a.x); o[1]=(short)f2b(a.y); o[2]=(short)f2b(a.z); o[3]=(short)f2b(a.w);
  o[4]=(short)f2b(b.x); o[5]=(short)f2b(b.y); o[6]=(short)f2b(b.z); o[7]=(short)f2b(b.w);
  return o;
}

// ---------------------------------------------------------------------------
// Dispatch 0: streaming prep. [0,1024): ST build; [1024,2560): A->bf16;
// [2560,2816): W->bf16.
// ---------------------------------------------------------------------------
__global__ __launch_bounds__(256) void prep(
    const float* __restrict__ dist, const float* __restrict__ adjm,
    const int* __restrict__ mask,
    const float* __restrict__ query, const float* __restrict__ key_,
    const float* __restrict__ value,
    const float* __restrict__ Wq, const float* __restrict__ Wk,
    const float* __restrict__ Wv, const float* __restrict__ Wo)
{
  const int bid = blockIdx.x;
  const int t   = threadIdx.x;

  if (bid < 1024){
    // ---- ST build: block = (b,qt,half): 8 rows x 512 k ----
    const int s = bid;
    const int b = (s >> 1) & 15, qt = s >> 5, half = s & 1;
    const int row = half*8 + (t >> 5);    // t>>5 in [0,8)
    const int seg = t & 31;
    const size_t roff = ((size_t)(b*N_ + qt*16 + row))*N_ + seg*16;
    const float* dp = dist + roff;
    const float* ap = adjm + roff;
    const int*   mp = mask + b*N_ + seg*16;
    const float4 d0 = reinterpret_cast<const float4*>(dp)[0];
    const float4 d1 = reinterpret_cast<const float4*>(dp)[1];
    const float4 d2 = reinterpret_cast<const float4*>(dp)[2];
    const float4 d3 = reinterpret_cast<const float4*>(dp)[3];
    const float4 a0 = reinterpret_cast<const float4*>(ap)[0];
    const float4 a1 = reinterpret_cast<const float4*>(ap)[1];
    const float4 a2 = reinterpret_cast<const float4*>(ap)[2];
    const float4 a3 = reinterpret_cast<const float4*>(ap)[3];
    const int4   m0 = reinterpret_cast<const int4*>(mp)[0];
    const int4   m1 = reinterpret_cast<const int4*>(mp)[1];
    const int4   m2 = reinterpret_cast<const int4*>(mp)[2];
    const int4   m3 = reinterpret_cast<const int4*>(mp)[3];

    float ev[16], av[16];
    #define ST_STEP(i, d4, a4, m4) \
      ev[i+0] = m4.x ? __expf(-d4.x) : 0.f;  av[i+0] = a4.x; \
      ev[i+1] = m4.y ? __expf(-d4.y) : 0.f;  av[i+1] = a4.y; \
      ev[i+2] = m4.z ? __expf(-d4.z) : 0.f;  av[i+2] = a4.z; \
      ev[i+3] = m4.w ? __expf(-d4.w) : 0.f;  av[i+3] = a4.w;
    ST_STEP(0,  d0, a0, m0)
    ST_STEP(4,  d1, a1, m1)
    ST_STEP(8,  d2, a2, m2)
    ST_STEP(12, d3, a3, m3)
    #undef ST_STEP
    float lz = 0.f, la = 0.f;
    #pragma unroll
    for (int i = 0; i < 16; ++i){ lz += ev[i]; la += av[i]; }
    #pragma unroll
    for (int o = 1; o < 32; o <<= 1){   // 32 lanes share a row (bits 0..4)
      lz += __shfl_xor(lz, o, 64);
      la += __shfl_xor(la, o, 64);
    }
    const float c0 = (lz > 0.f) ? 0.3f / lz : 0.f;
    const float c1 = 0.4f / (la + 1e-6f);
    v8s s0v, s1v;
    #pragma unroll
    for (int i = 0; i < 8; ++i){
      s0v[i] = (short)f2b(ev[i]*c0   + av[i]*c1);
      s1v[i] = (short)f2b(ev[8+i]*c0 + av[8+i]*c1);
    }
    *reinterpret_cast<v8s*>(g_ST + roff)     = s0v;
    *reinterpret_cast<v8s*>(g_ST + roff + 8) = s1v;
    return;
  }

  if (bid < 2560){
    // ---- A conversion: 512 blocks per tensor, 16 elems/thread ----
    const int a = bid - 1024;
    const int z = a >> 9;                 // 0:q 1:k 2:v
    const int blk = a & 511;
    const size_t base = ((size_t)blk*256 + t) * 16;
    const float* src = (z==0)?query:(z==1)?key_:value;
    const float4 u0 = reinterpret_cast<const float4*>(src + base)[0];
    const float4 u1 = reinterpret_cast<const float4*>(src + base)[1];
    const float4 u2 = reinterpret_cast<const float4*>(src + base)[2];
    const float4 u3 = reinterpret_cast<const float4*>(src + base)[3];
    unsigned short* dst = g_Ain + (size_t)z*QKV_ELEMS + base;
    *reinterpret_cast<v8s*>(dst)     = pack8(u0, u1);
    *reinterpret_cast<v8s*>(dst + 8) = pack8(u2, u3);
    return;
  }

  // ---- W conversion: 256 blocks x 256 thr, 4 elems/thread ----
  const int wb = bid - 2560;
  const int z = wb >> 6;                     // 0:Wq 1:Wk 2:Wv 3:Wo
  const int i = ((wb & 63)*256 + t)*4;
  const float* src = (z==0)?Wq:(z==1)?Wk:(z==2)?Wv:Wo;
  const float4 u = *reinterpret_cast<const float4*>(src + i);
  ushort4 o4;
  o4.x = f2b(u.x); o4.y = f2b(u.y); o4.z = f2b(u.z); o4.w = f2b(u.w);
  if (z < 3){
    unsigned short* dst = (z==0)?g_WqB:(z==1)?g_WkB:g_WvB;
    *reinterpret_cast<ushort4*>(dst + i) = o4;
  } else {
    const int n = i >> 8, k = i & 255;
    *reinterpret_cast<ushort4*>(g_WoB + ((size_t)(k >> 5))*8192 + (size_t)n*32 + (k & 31)) = o4;
  }
}

// ---------------------------------------------------------------------------
// Dispatch 1: QKV GEMM (LDS-staged W, bf16 A).
// C[m][n] = sum_k A[m][k]*W[n][k] + b[n], M=8192, N=K=256.
// ---------------------------------------------------------------------------
__global__ __launch_bounds__(256) void qkv_gemm(
    const float* __restrict__ bq, const float* __restrict__ bk,
    const float* __restrict__ bv)
{
  __shared__ unsigned short Wl[64*264];   // 33.8 KB
  const int bid0 = blockIdx.x;
  const int t    = threadIdx.x;
  // XCD-chunked swizzle: co-locate the 4 A-sharing blocks
  const int bid = ((bid0 & 7) * 192) + (bid0 >> 3);   // bijective on [0,1536)
  const int z  = bid >> 9;                 // 0:Q 1:K 2:V
  const int rr = bid & 511;
  const int mt = rr >> 2, nt = rr & 3;     // nt fastest: 4 consecutive share A
  const unsigned short* Ap = g_Ain + (size_t)z*QKV_ELEMS;
  const unsigned short* WB = (z==0) ? g_WqB : (z==1) ? g_WkB : g_WvB;
  const float* bp = (z==0) ? bq : (z==1) ? bk : bv;
  const int w = t >> 6, lane = t & 63, kl = lane & 15, quad = lane >> 4;
  const int m0 = mt*64 + w*16;
  const int n0 = nt*64;

  {   // stage bf16 W tile [n0..n0+63][0..255]
    const int row = t >> 2;
    const int ks  = (t & 3) * 64;
    const unsigned short* src = WB + (size_t)(n0+row)*256 + ks;
    unsigned short* dst = Wl + row*264 + ks;
    #pragma unroll
    for (int u = 0; u < 8; ++u)
      *reinterpret_cast<v8s*>(dst + u*8) = *reinterpret_cast<const v8s*>(src + u*8);
  }
  __syncthreads();

  v4f acc[4];
  #pragma unroll
  for (int nb = 0; nb < 4; ++nb) acc[nb] = (v4f){0.f,0.f,0.f,0.f};
  const int arow = m0 + kl;

  if (z == 2){
    #pragma unroll
    for (int k0 = 0; k0 < 256; k0 += 32){
      const v8s af = *reinterpret_cast<const v8s*>(Ap + (size_t)arow*256 + k0 + quad*8);
      #pragma unroll
      for (int nb = 0; nb < 4; ++nb){
        const v8s wf = *reinterpret_cast<const v8s*>(&Wl[(nb*16+kl)*264 + k0 + quad*8]);
        acc[nb] = __builtin_amdgcn_mfma_f32_16x16x32_bf16(wf, af, acc[nb], 0, 0, 0);
      }
    }
    // D[n][tok]; tile-interleaved store: [bb,h, tokblk, dk, tok&31]
    const int tok = m0 + kl, bb = tok >> 9, nr = tok & 511;
    #pragma unroll
    for (int nb = 0; nb < 4; ++nb)
      #pragma unroll
      for (int r = 0; r < 4; ++r){
        const int n = n0 + nb*16 + quad*4 + r;
        const float v = acc[nb][r] + bp[n];
        g_VT[(((size_t)bb*H_ + (n>>5))*16 + (nr>>5))*1024 + (size_t)(n&31)*32 + (nr&31)] = f2b(v);
      }
  } else {
    #pragma unroll
    for (int k0 = 0; k0 < 256; k0 += 32){
      const v8s af = *reinterpret_cast<const v8s*>(Ap + (size_t)arow*256 + k0 + quad*8);
      #pragma unroll
      for (int nb = 0; nb < 4; ++nb){
        const v8s wf = *reinterpret_cast<const v8s*>(&Wl[(nb*16+kl)*264 + k0 + quad*8]);
        acc[nb] = __builtin_amdgcn_mfma_f32_16x16x32_bf16(af, wf, acc[nb], 0, 0, 0);
      }
    }
    unsigned short* dst = z ? g_Kb : g_Qb;
    const float sc = (z == 0) ? QSCALE : 1.0f;   // fold 1/sqrt(dk)*log2e into Q
    #pragma unroll
    for (int nb = 0; nb < 4; ++nb){
      const int n = n0 + nb*16 + kl;
      const float bias = bp[n];
      #pragma unroll
      for (int r = 0; r < 4; ++r){
        const int m = m0 + quad*4 + r;
        const float v = (acc[nb][r] + bias) * sc;
        dst[(((size_t)(m>>9)*H_ + (n>>5))*N_ + (m&511))*DK_ + (n&31)] = f2b(v);
      }
    }
  }
}

// ---------------------------------------------------------------------------
// Dispatch 2: attention. 512 thr = 8 waves = 8 heads; one (b,qtile).
// Swapped QK^T -> in-register P transpose (cvt_pk + shfl). No P LDS.
// ---------------------------------------------------------------------------
__global__ __launch_bounds__(512, 4) void attn_kernel(
    const int* __restrict__ mask, const float* __restrict__ bo,
    float* __restrict__ out)
{
  __shared__ unsigned short STl[16*520];    // 16.6 KB  ST[qrow][k] bf16 (padded)
  __shared__ unsigned short Xl[16*272];     //  8.7 KB  X[qrow][n] bf16
  const int bid = blockIdx.x;
  const int b  = bid & 15;                  // same-b -> same XCD (K/V L2 reuse)
  const int qt = bid >> 4;
  const int q0 = qt*16;
  const int t  = threadIdx.x;
  const int w  = t >> 6, lane = t & 63;
  const int kl = lane & 15, quad = lane >> 4;

  // ---- stage precomputed ST tile (16KB bf16, L2/L3-hot) into padded LDS ----
  {
    const int row = t >> 5;                 // 16 rows, 32 thr each
    const int c16 = (t & 31) * 16;
    const unsigned short* src = g_ST + ((size_t)(b*N_ + q0 + row))*N_ + c16;
    *reinterpret_cast<v8s*>(&STl[row*520 + c16])     = *reinterpret_cast<const v8s*>(src);
    *reinterpret_cast<v8s*>(&STl[row*520 + c16 + 8]) = *reinterpret_cast<const v8s*>(src + 8);
  }

  const int h = w;
  const size_t bh = (size_t)b*H_ + h;
  const unsigned short* Qp = g_Qb + (bh*N_ + q0)*DK_;
  const unsigned short* Kp = g_Kb + bh*N_*DK_;
  const unsigned short* Vp = g_VT + bh*(size_t)(N_*DK_);
  const int* mrow = mask + b*N_;
  const v8s aq = *reinterpret_cast<const v8s*>(Qp + (size_t)kl*DK_ + quad*8);
  const v4f vz = {0.f, 0.f, 0.f, 0.f};

  // src lanes for the P transpose shuffles
  const int s0 = ((quad & 1) << 5) + kl;    // quads {0,1} or {2,3} low half
  const int s1 = s0 + 16;
  const int hi = quad >> 1;                 // kb parity select

  v4f oA0 = vz, oA1 = vz;     // attention PV (unnormalized)
  v4f oS0 = vz, oS1 = vz;     // ST PV (pre-scaled)
  float lsum = 0.f;

  __syncthreads();            // STl visible to all waves

  #pragma unroll 1
  for (int ch = 0; ch < 4; ++ch){
    const int k0 = ch*128;
    // QK^T, swapped operands: acc[kb][r] = P[key=k0+kb*16+quad*4+r][q=kl]
    v4f acc[8];
    #pragma unroll
    for (int kb = 0; kb < 8; ++kb){
      const v8s bk = *reinterpret_cast<const v8s*>(Kp + (size_t)(k0 + kb*16 + kl)*DK_ + quad*8);
      acc[kb] = __builtin_amdgcn_mfma_f32_16x16x32_bf16(bk, aq, vz, 0, 0, 0);
    }
    // prefetch V fragments (global, L2-hot) before the VALU exp phase
    v8s av[8];
    #pragma unroll
    for (int cc = 0; cc < 4; ++cc){
      const int kk = k0 + cc*32;
      av[2*cc]   = *reinterpret_cast<const v8s*>(Vp + (size_t)(kk + kl)*32 + quad*8);
      av[2*cc+1] = *reinterpret_cast<const v8s*>(Vp + (size_t)(kk + 16 + kl)*32 + quad*8);
    }
    // exp2 (Q pre-scaled by 1/sqrt(dk)*log2e); key = k0+kb*16+quad*4+r
    #pragma unroll
    for (int kb = 0; kb < 8; ++kb){
      const int4 m4 = *reinterpret_cast<const int4*>(mrow + k0 + kb*16 + quad*4);
      const float e0 = m4.x ? __builtin_amdgcn_exp2f(acc[kb][0]) : 0.f;
      const float e1 = m4.y ? __builtin_amdgcn_exp2f(acc[kb][1]) : 0.f;
      const float e2 = m4.z ? __builtin_amdgcn_exp2f(acc[kb][2]) : 0.f;
      const float e3 = m4.w ? __builtin_amdgcn_exp2f(acc[kb][3]) : 0.f;
      acc[kb][0]=e0; acc[kb][1]=e1; acc[kb][2]=e2; acc[kb][3]=e3;
      lsum += e0+e1+e2+e3;
    }
    // PV with in-register P transpose
    #pragma unroll
    for (int cc = 0; cc < 4; ++cc){
      const int kk = k0 + cc*32;
      uint32_t pkE0, pkE2, pkO0, pkO2;
      asm("v_cvt_pk_bf16_f32 %0, %1, %2" : "=v"(pkE0) : "v"(acc[2*cc][0]),   "v"(acc[2*cc][1]));
      asm("v_cvt_pk_bf16_f32 %0, %1, %2" : "=v"(pkE2) : "v"(acc[2*cc][2]),   "v"(acc[2*cc][3]));
      asm("v_cvt_pk_bf16_f32 %0, %1, %2" : "=v"(pkO0) : "v"(acc[2*cc+1][0]), "v"(acc[2*cc+1][1]));
      asm("v_cvt_pk_bf16_f32 %0, %1, %2" : "=v"(pkO2) : "v"(acc[2*cc+1][2]), "v"(acc[2*cc+1][3]));
      const uint32_t e0a = (uint32_t)__shfl((int)pkE0, s0, 64);
      const uint32_t o0a = (uint32_t)__shfl((int)pkO0, s0, 64);
      const uint32_t e2a = (uint32_t)__shfl((int)pkE2, s0, 64);
      const uint32_t o2a = (uint32_t)__shfl((int)pkO2, s0, 64);
      const uint32_t e0b = (uint32_t)__shfl((int)pkE0, s1, 64);
      const uint32_t o0b = (uint32_t)__shfl((int)pkO0, s1, 64);
      const uint32_t e2b = (uint32_t)__shfl((int)pkE2, s1, 64);
      const uint32_t o2b = (uint32_t)__shfl((int)pkO2, s1, 64);
      union { v8s v; uint32_t w4[4]; } bp;
      bp.w4[0] = hi ? o0a : e0a;
      bp.w4[1] = hi ? o2a : e2a;
      bp.w4[2] = hi ? o0b : e0b;
      bp.w4[3] = hi ? o2b : e2b;
      const v8s bst = *reinterpret_cast<const v8s*>(&STl[kl*520 + kk + quad*8]);
      oA0 = __builtin_amdgcn_mfma_f32_16x16x32_bf16(av[2*cc],   bp.v, oA0, 0, 0, 0);
      oS0 = __builtin_amdgcn_mfma_f32_16x16x32_bf16(av[2*cc],   bst,  oS0, 0, 0, 0);
      oA1 = __builtin_amdgcn_mfma_f32_16x16x32_bf16(av[2*cc+1], bp.v, oA1, 0, 0, 0);
      oS1 = __builtin_amdgcn_mfma_f32_16x16x32_bf16(av[2*cc+1], bst,  oS1, 0, 0, 0);
    }
  }

  // full-row softmax denominator for q = kl: reduce across quads (bits 4,5)
  lsum += __shfl_xor(lsum, 16, 64);
  lsum += __shfl_xor(lsum, 32, 64);
  const float inv = (lsum > 0.f) ? 0.3f / lsum : 0.f;

  // X[qrow=kl][n = h*32 + d'] bf16 into LDS (lane holds O^T[d'][q=kl])
  unsigned short* xr = Xl + kl*272 + h*32;
  #pragma unroll
  for (int r = 0; r < 4; ++r){
    xr[     quad*4 + r] = f2b(oA0[r]*inv + oS0[r]);
    xr[16 + quad*4 + r] = f2b(oA1[r]*inv + oS1[r]);
  }
  __syncthreads();

  // ---- Phase C: out = X @ Wo^T + bo, wave w -> n in [w*32, w*32+32) ----
  {
    const int n0 = w*32;
    v4f a2[2];
    a2[0] = vz; a2[1] = vz;
    #pragma unroll
    for (int k0 = 0; k0 < 256; k0 += 32){
      const v8s af = *reinterpret_cast<const v8s*>(&Xl[kl*272 + k0 + quad*8]);
      #pragma unroll
      for (int nb = 0; nb < 2; ++nb){
        const v8s wf = *reinterpret_cast<const v8s*>(
            g_WoB + (size_t)(k0 >> 5)*8192 + (size_t)(n0 + nb*16 + kl)*32 + quad*8);
        a2[nb] = __builtin_amdgcn_mfma_f32_16x16x32_bf16(af, wf, a2[nb], 0, 0, 0);
      }
    }
    #pragma unroll
    for (int nb = 0; nb < 2; ++nb){
      const int n = n0 + nb*16 + kl;
      const float bias = bo[n];
      #pragma unroll
      for (int r = 0; r < 4; ++r)
        out[((size_t)(b*N_ + q0 + quad*4 + r))*256 + n] = a2[nb][r] + bias;
    }
  }
}

extern "C" void kernel_launch(void* const* d_in, const int* in_sizes, int n_in,
                              void* d_out, int out_size, void* d_ws, size_t ws_size,
                              hipStream_t stream)
{
  const float* query = (const float*)d_in[0];
  const float* key_  = (const float*)d_in[1];
  const float* value = (const float*)d_in[2];
  const float* adjm  = (const float*)d_in[3];
  const float* dist  = (const float*)d_in[4];
  // d_in[5] = edges_att (unused)
  const int*   mask  = (const int*)d_in[6];
  const float* Wq = (const float*)d_in[7];  const float* bq = (const float*)d_in[8];
  const float* Wk = (const float*)d_in[9];  const float* bk = (const float*)d_in[10];
  const float* Wv = (const float*)d_in[11]; const float* bv = (const float*)d_in[12];
  const float* Wo = (const float*)d_in[13]; const float* bo = (const float*)d_in[14];

  prep<<<2816, 256, 0, stream>>>(dist, adjm, mask, query, key_, value,
                                 Wq, Wk, Wv, Wo);
  qkv_gemm<<<1536, 256, 0, stream>>>(bq, bk, bv);
  attn_kernel<<<512, 512, 0, stream>>>(mask, bo, (float*)d_out);
}

// Round 12
// 159.704 us; speedup vs baseline: 2.1076x; 1.0182x over previous
//
#include <hip/hip_runtime.h>
#include <cstdint>
#include <cstddef>

#define B_  16
#define N_  512
#define D_  256
#define H_  8
#define DK_ 32
// Round 20: prep TLP restructure (final unexplored lever).
// Theory: every multi-role streaming kernel this session compiled to a
// ~32-VGPR serialized schedule (r10: 0.76TB/s, r11: 0.5TB/s, r9: 2.1TB/s
// vs 6.5TB/s for the 8-VGPR fill). Current prep's ST branch needs 12
// in-flight loads -> likely starved -> prep ~45us of the ~87us kernel sum.
// Fix: make each role NEED <=28 VGPR so stingy regalloc is harmless:
//  - ST build: one WAVE per q-row (lane = 8-elem seg, full-wave shfl
//    reduce), 6 loads/thread, 2048 blocks x 256 thr.
//  - A-conv: 8 elems/thread (2 loads + 1 store), 3072 blocks.
//  - W-conv: 4 elems/thread, 256 blocks.
// One 5376-block kernel; 3x the TLP of r19's prep. Math bit-identical.
// qkv_gemm / attn_kernel: byte-identical controls (r15-best structure).

#define QKV_ELEMS 2097152   // B*N*D

__device__ __align__(16) unsigned short g_Qb[QKV_ELEMS];   // [B,H,N,DK] bf16 (pre-scaled)
__device__ __align__(16) unsigned short g_Kb[QKV_ELEMS];   // [B,H,N,DK] bf16
__device__ __align__(16) unsigned short g_VT[QKV_ELEMS];   // [B,H,tokblk,DK,tok32] bf16
__device__ __align__(16) unsigned short g_Ain[3*QKV_ELEMS];// q/k/v inputs bf16
__device__ __align__(16) unsigned short g_WqB[D_*D_];      // Wq bf16 [n][k]
__device__ __align__(16) unsigned short g_WkB[D_*D_];      // Wk bf16 [n][k]
__device__ __align__(16) unsigned short g_WvB[D_*D_];      // Wv bf16 [n][k]
__device__ __align__(16) unsigned short g_WoB[D_*D_];      // Wo bf16 [k>>5][n][k&31]
__device__ __align__(16) unsigned short g_ST[B_*N_*N_];    // blended dist/adj bf16 [b][q][k]

typedef short v8s __attribute__((ext_vector_type(8)));
typedef float v4f __attribute__((ext_vector_type(4)));

// 1/sqrt(32) * log2(e): Q pre-scale so attn uses exp2 directly
#define QSCALE 0.25503485917270874f

__device__ __forceinline__ unsigned short f2b(float f){
  unsigned int x;
  __builtin_memcpy(&x, &f, 4);
  x = x + 0x7FFFu + ((x >> 16) & 1u);   // round-to-nearest-even
  return (unsigned short)(x >> 16);
}
__device__ __forceinline__ v8s pack8(const float4 a, const float4 b){
  v8s o;
  o[0]=(short)f2b(a.x); o[1]=(short)f2b(a.y); o[2]=(short)f2b(a.z); o[3]=(short)f2b(a.w);
  o[4]=(short)f2b(b.x); o[5]=(short)f2b(b.y); o[6]=(short)f2b(b.z); o[7]=(short)f2b(b.w);
  return o;
}

// ---------------------------------------------------------------------------
// Dispatch 0: streaming prep, minimal per-thread state in every role.
// [0,2048): ST build (wave = one q-row). [2048,5120): A->bf16 (8/thread).
// [5120,5376): W->bf16 (4/thread).
// ---------------------------------------------------------------------------
__global__ __launch_bounds__(256) void prep(
    const float* __restrict__ dist, const float* __restrict__ adjm,
    const int* __restrict__ mask,
    const float* __restrict__ query, const float* __restrict__ key_,
    const float* __restrict__ value,
    const float* __restrict__ Wq, const float* __restrict__ Wk,
    const float* __restrict__ Wv, const float* __restrict__ Wo)
{
  const int bid = blockIdx.x;
  const int t   = threadIdx.x;

  if (bid < 2048){
    // ---- ST build: 4 waves/block, wave = one global row (b*N+q) ----
    const int w = t >> 6, lane = t & 63;
    const int rowg = bid*4 + w;                 // b*N_ + q
    const int b = rowg >> 9;
    const size_t roff = (size_t)rowg*N_ + lane*8;
    const float* dp = dist + roff;
    const float* ap = adjm + roff;
    const int*   mp = mask + b*N_ + lane*8;
    const float4 d0 = reinterpret_cast<const float4*>(dp)[0];
    const float4 d1 = reinterpret_cast<const float4*>(dp)[1];
    const float4 a0 = reinterpret_cast<const float4*>(ap)[0];
    const float4 a1 = reinterpret_cast<const float4*>(ap)[1];
    const int4   m0 = reinterpret_cast<const int4*>(mp)[0];
    const int4   m1 = reinterpret_cast<const int4*>(mp)[1];

    float ev[8], av[8];
    ev[0] = m0.x ? __expf(-d0.x) : 0.f;  av[0] = a0.x;
    ev[1] = m0.y ? __expf(-d0.y) : 0.f;  av[1] = a0.y;
    ev[2] = m0.z ? __expf(-d0.z) : 0.f;  av[2] = a0.z;
    ev[3] = m0.w ? __expf(-d0.w) : 0.f;  av[3] = a0.w;
    ev[4] = m1.x ? __expf(-d1.x) : 0.f;  av[4] = a1.x;
    ev[5] = m1.y ? __expf(-d1.y) : 0.f;  av[5] = a1.y;
    ev[6] = m1.z ? __expf(-d1.z) : 0.f;  av[6] = a1.z;
    ev[7] = m1.w ? __expf(-d1.w) : 0.f;  av[7] = a1.w;

    float lz = 0.f, la = 0.f;
    #pragma unroll
    for (int i = 0; i < 8; ++i){ lz += ev[i]; la += av[i]; }
    #pragma unroll
    for (int o = 1; o < 64; o <<= 1){           // full-wave reduce (row = wave)
      lz += __shfl_xor(lz, o, 64);
      la += __shfl_xor(la, o, 64);
    }
    const float c0 = (lz > 0.f) ? 0.3f / lz : 0.f;
    const float c1 = 0.4f / (la + 1e-6f);
    v8s s;
    #pragma unroll
    for (int i = 0; i < 8; ++i)
      s[i] = (short)f2b(ev[i]*c0 + av[i]*c1);
    *reinterpret_cast<v8s*>(g_ST + roff) = s;
    return;
  }

  if (bid < 5120){
    // ---- A conversion: 8 elems/thread; 2^18 threads per tensor ----
    const int tid = (bid - 2048)*256 + t;       // [0, 786432)
    const int z = tid >> 18;                    // 0:q 1:k 2:v
    const size_t lo = (size_t)(tid & 262143) * 8;
    const float* src = (z==0)?query:(z==1)?key_:value;
    const float4 u0 = reinterpret_cast<const float4*>(src + lo)[0];
    const float4 u1 = reinterpret_cast<const float4*>(src + lo)[1];
    *reinterpret_cast<v8s*>(g_Ain + (size_t)z*QKV_ELEMS + lo) = pack8(u0, u1);
    return;
  }

  // ---- W conversion: 256 blocks x 256 thr, 4 elems/thread ----
  const int wb = bid - 5120;
  const int z = wb >> 6;                     // 0:Wq 1:Wk 2:Wv 3:Wo
  const int i = ((wb & 63)*256 + t)*4;
  const float* src = (z==0)?Wq:(z==1)?Wk:(z==2)?Wv:Wo;
  const float4 u = *reinterpret_cast<const float4*>(src + i);
  ushort4 o4;
  o4.x = f2b(u.x); o4.y = f2b(u.y); o4.z = f2b(u.z); o4.w = f2b(u.w);
  if (z < 3){
    unsigned short* dst = (z==0)?g_WqB:(z==1)?g_WkB:g_WvB;
    *reinterpret_cast<ushort4*>(dst + i) = o4;
  } else {
    const int n = i >> 8, k = i & 255;
    *reinterpret_cast<ushort4*>(g_WoB + ((size_t)(k >> 5))*8192 + (size_t)n*32 + (k & 31)) = o4;
  }
}

// ---------------------------------------------------------------------------
// Dispatch 1: QKV GEMM (LDS-staged W, bf16 A) — byte-identical control.
// C[m][n] = sum_k A[m][k]*W[n][k] + b[n], M=8192, N=K=256.
// ---------------------------------------------------------------------------
__global__ __launch_bounds__(256) void qkv_gemm(
    const float* __restrict__ bq, const float* __restrict__ bk,
    const float* __restrict__ bv)
{
  __shared__ unsigned short Wl[64*264];   // 33.8 KB
  const int bid0 = blockIdx.x;
  const int t    = threadIdx.x;
  // XCD-chunked swizzle: co-locate the 4 A-sharing blocks
  const int bid = ((bid0 & 7) * 192) + (bid0 >> 3);   // bijective on [0,1536)
  const int z  = bid >> 9;                 // 0:Q 1:K 2:V
  const int rr = bid & 511;
  const int mt = rr >> 2, nt = rr & 3;     // nt fastest: 4 consecutive share A
  const unsigned short* Ap = g_Ain + (size_t)z*QKV_ELEMS;
  const unsigned short* WB = (z==0) ? g_WqB : (z==1) ? g_WkB : g_WvB;
  const float* bp = (z==0) ? bq : (z==1) ? bk : bv;
  const int w = t >> 6, lane = t & 63, kl = lane & 15, quad = lane >> 4;
  const int m0 = mt*64 + w*16;
  const int n0 = nt*64;

  {   // stage bf16 W tile [n0..n0+63][0..255]
    const int row = t >> 2;
    const int ks  = (t & 3) * 64;
    const unsigned short* src = WB + (size_t)(n0+row)*256 + ks;
    unsigned short* dst = Wl + row*264 + ks;
    #pragma unroll
    for (int u = 0; u < 8; ++u)
      *reinterpret_cast<v8s*>(dst + u*8) = *reinterpret_cast<const v8s*>(src + u*8);
  }
  __syncthreads();

  v4f acc[4];
  #pragma unroll
  for (int nb = 0; nb < 4; ++nb) acc[nb] = (v4f){0.f,0.f,0.f,0.f};
  const int arow = m0 + kl;

  if (z == 2){
    #pragma unroll
    for (int k0 = 0; k0 < 256; k0 += 32){
      const v8s af = *reinterpret_cast<const v8s*>(Ap + (size_t)arow*256 + k0 + quad*8);
      #pragma unroll
      for (int nb = 0; nb < 4; ++nb){
        const v8s wf = *reinterpret_cast<const v8s*>(&Wl[(nb*16+kl)*264 + k0 + quad*8]);
        acc[nb] = __builtin_amdgcn_mfma_f32_16x16x32_bf16(wf, af, acc[nb], 0, 0, 0);
      }
    }
    // D[n][tok]; tile-interleaved store: [bb,h, tokblk, dk, tok&31]
    const int tok = m0 + kl, bb = tok >> 9, nr = tok & 511;
    #pragma unroll
    for (int nb = 0; nb < 4; ++nb)
      #pragma unroll
      for (int r = 0; r < 4; ++r){
        const int n = n0 + nb*16 + quad*4 + r;
        const float v = acc[nb][r] + bp[n];
        g_VT[(((size_t)bb*H_ + (n>>5))*16 + (nr>>5))*1024 + (size_t)(n&31)*32 + (nr&31)] = f2b(v);
      }
  } else {
    #pragma unroll
    for (int k0 = 0; k0 < 256; k0 += 32){
      const v8s af = *reinterpret_cast<const v8s*>(Ap + (size_t)arow*256 + k0 + quad*8);
      #pragma unroll
      for (int nb = 0; nb < 4; ++nb){
        const v8s wf = *reinterpret_cast<const v8s*>(&Wl[(nb*16+kl)*264 + k0 + quad*8]);
        acc[nb] = __builtin_amdgcn_mfma_f32_16x16x32_bf16(af, wf, acc[nb], 0, 0, 0);
      }
    }
    unsigned short* dst = z ? g_Kb : g_Qb;
    const float sc = (z == 0) ? QSCALE : 1.0f;   // fold 1/sqrt(dk)*log2e into Q
    #pragma unroll
    for (int nb = 0; nb < 4; ++nb){
      const int n = n0 + nb*16 + kl;
      const float bias = bp[n];
      #pragma unroll
      for (int r = 0; r < 4; ++r){
        const int m = m0 + quad*4 + r;
        const float v = (acc[nb][r] + bias) * sc;
        dst[(((size_t)(m>>9)*H_ + (n>>5))*N_ + (m&511))*DK_ + (n&31)] = f2b(v);
      }
    }
  }
}

// ---------------------------------------------------------------------------
// Dispatch 2: attention — byte-identical control.
// 512 thr = 8 waves = 8 heads; one (b,qtile). Swapped QK^T -> in-register
// P transpose (cvt_pk + shfl). No P LDS.
// ---------------------------------------------------------------------------
__global__ __launch_bounds__(512, 4) void attn_kernel(
    const int* __restrict__ mask, const float* __restrict__ bo,
    float* __restrict__ out)
{
  __shared__ unsigned short STl[16*520];    // 16.6 KB  ST[qrow][k] bf16 (padded)
  __shared__ unsigned short Xl[16*272];     //  8.7 KB  X[qrow][n] bf16
  const int bid = blockIdx.x;
  const int b  = bid & 15;                  // same-b -> same XCD (K/V L2 reuse)
  const int qt = bid >> 4;
  const int q0 = qt*16;
  const int t  = threadIdx.x;
  const int w  = t >> 6, lane = t & 63;
  const int kl = lane & 15, quad = lane >> 4;

  // ---- stage precomputed ST tile (16KB bf16, L2/L3-hot) into padded LDS ----
  {
    const int row = t >> 5;                 // 16 rows, 32 thr each
    const int c16 = (t & 31) * 16;
    const unsigned short* src = g_ST + ((size_t)(b*N_ + q0 + row))*N_ + c16;
    *reinterpret_cast<v8s*>(&STl[row*520 + c16])     = *reinterpret_cast<const v8s*>(src);
    *reinterpret_cast<v8s*>(&STl[row*520 + c16 + 8]) = *reinterpret_cast<const v8s*>(src + 8);
  }

  const int h = w;
  const size_t bh = (size_t)b*H_ + h;
  const unsigned short* Qp = g_Qb + (bh*N_ + q0)*DK_;
  const unsigned short* Kp = g_Kb + bh*N_*DK_;
  const unsigned short* Vp = g_VT + bh*(size_t)(N_*DK_);
  const int* mrow = mask + b*N_;
  const v8s aq = *reinterpret_cast<const v8s*>(Qp + (size_t)kl*DK_ + quad*8);
  const v4f vz = {0.f, 0.f, 0.f, 0.f};

  // src lanes for the P transpose shuffles
  const int s0 = ((quad & 1) << 5) + kl;    // quads {0,1} or {2,3} low half
  const int s1 = s0 + 16;
  const int hi = quad >> 1;                 // kb parity select

  v4f oA0 = vz, oA1 = vz;     // attention PV (unnormalized)
  v4f oS0 = vz, oS1 = vz;     // ST PV (pre-scaled)
  float lsum = 0.f;

  __syncthreads();            // STl visible to all waves

  #pragma unroll 1
  for (int ch = 0; ch < 4; ++ch){
    const int k0 = ch*128;
    // QK^T, swapped operands: acc[kb][r] = P[key=k0+kb*16+quad*4+r][q=kl]
    v4f acc[8];
    #pragma unroll
    for (int kb = 0; kb < 8; ++kb){
      const v8s bk = *reinterpret_cast<const v8s*>(Kp + (size_t)(k0 + kb*16 + kl)*DK_ + quad*8);
      acc[kb] = __builtin_amdgcn_mfma_f32_16x16x32_bf16(bk, aq, vz, 0, 0, 0);
    }
    // prefetch V fragments (global, L2-hot) before the VALU exp phase
    v8s av[8];
    #pragma unroll
    for (int cc = 0; cc < 4; ++cc){
      const int kk = k0 + cc*32;
      av[2*cc]   = *reinterpret_cast<const v8s*>(Vp + (size_t)(kk + kl)*32 + quad*8);
      av[2*cc+1] = *reinterpret_cast<const v8s*>(Vp + (size_t)(kk + 16 + kl)*32 + quad*8);
    }
    // exp2 (Q pre-scaled by 1/sqrt(dk)*log2e); key = k0+kb*16+quad*4+r
    #pragma unroll
    for (int kb = 0; kb < 8; ++kb){
      const int4 m4 = *reinterpret_cast<const int4*>(mrow + k0 + kb*16 + quad*4);
      const float e0 = m4.x ? __builtin_amdgcn_exp2f(acc[kb][0]) : 0.f;
      const float e1 = m4.y ? __builtin_amdgcn_exp2f(acc[kb][1]) : 0.f;
      const float e2 = m4.z ? __builtin_amdgcn_exp2f(acc[kb][2]) : 0.f;
      const float e3 = m4.w ? __builtin_amdgcn_exp2f(acc[kb][3]) : 0.f;
      acc[kb][0]=e0; acc[kb][1]=e1; acc[kb][2]=e2; acc[kb][3]=e3;
      lsum += e0+e1+e2+e3;
    }
    // PV with in-register P transpose
    #pragma unroll
    for (int cc = 0; cc < 4; ++cc){
      const int kk = k0 + cc*32;
      uint32_t pkE0, pkE2, pkO0, pkO2;
      asm("v_cvt_pk_bf16_f32 %0, %1, %2" : "=v"(pkE0) : "v"(acc[2*cc][0]),   "v"(acc[2*cc][1]));
      asm("v_cvt_pk_bf16_f32 %0, %1, %2" : "=v"(pkE2) : "v"(acc[2*cc][2]),   "v"(acc[2*cc][3]));
      asm("v_cvt_pk_bf16_f32 %0, %1, %2" : "=v"(pkO0) : "v"(acc[2*cc+1][0]), "v"(acc[2*cc+1][1]));
      asm("v_cvt_pk_bf16_f32 %0, %1, %2" : "=v"(pkO2) : "v"(acc[2*cc+1][2]), "v"(acc[2*cc+1][3]));
      const uint32_t e0a = (uint32_t)__shfl((int)pkE0, s0, 64);
      const uint32_t o0a = (uint32_t)__shfl((int)pkO0, s0, 64);
      const uint32_t e2a = (uint32_t)__shfl((int)pkE2, s0, 64);
      const uint32_t o2a = (uint32_t)__shfl((int)pkO2, s0, 64);
      const uint32_t e0b = (uint32_t)__shfl((int)pkE0, s1, 64);
      const uint32_t o0b = (uint32_t)__shfl((int)pkO0, s1, 64);
      const uint32_t e2b = (uint32_t)__shfl((int)pkE2, s1, 64);
      const uint32_t o2b = (uint32_t)__shfl((int)pkO2, s1, 64);
      union { v8s v; uint32_t w4[4]; } bp;
      bp.w4[0] = hi ? o0a : e0a;
      bp.w4[1] = hi ? o2a : e2a;
      bp.w4[2] = hi ? o0b : e0b;
      bp.w4[3] = hi ? o2b : e2b;
      const v8s bst = *reinterpret_cast<const v8s*>(&STl[kl*520 + kk + quad*8]);
      oA0 = __builtin_amdgcn_mfma_f32_16x16x32_bf16(av[2*cc],   bp.v, oA0, 0, 0, 0);
      oS0 = __builtin_amdgcn_mfma_f32_16x16x32_bf16(av[2*cc],   bst,  oS0, 0, 0, 0);
      oA1 = __builtin_amdgcn_mfma_f32_16x16x32_bf16(av[2*cc+1], bp.v, oA1, 0, 0, 0);
      oS1 = __builtin_amdgcn_mfma_f32_16x16x32_bf16(av[2*cc+1], bst,  oS1, 0, 0, 0);
    }
  }

  // full-row softmax denominator for q = kl: reduce across quads (bits 4,5)
  lsum += __shfl_xor(lsum, 16, 64);
  lsum += __shfl_xor(lsum, 32, 64);
  const float inv = (lsum > 0.f) ? 0.3f / lsum : 0.f;

  // X[qrow=kl][n = h*32 + d'] bf16 into LDS (lane holds O^T[d'][q=kl])
  unsigned short* xr = Xl + kl*272 + h*32;
  #pragma unroll
  for (int r = 0; r < 4; ++r){
    xr[     quad*4 + r] = f2b(oA0[r]*inv + oS0[r]);
    xr[16 + quad*4 + r] = f2b(oA1[r]*inv + oS1[r]);
  }
  __syncthreads();

  // ---- Phase C: out = X @ Wo^T + bo, wave w -> n in [w*32, w*32+32) ----
  {
    const int n0 = w*32;
    v4f a2[2];
    a2[0] = vz; a2[1] = vz;
    #pragma unroll
    for (int k0 = 0; k0 < 256; k0 += 32){
      const v8s af = *reinterpret_cast<const v8s*>(&Xl[kl*272 + k0 + quad*8]);
      #pragma unroll
      for (int nb = 0; nb < 2; ++nb){
        const v8s wf = *reinterpret_cast<const v8s*>(
            g_WoB + (size_t)(k0 >> 5)*8192 + (size_t)(n0 + nb*16 + kl)*32 + quad*8);
        a2[nb] = __builtin_amdgcn_mfma_f32_16x16x32_bf16(af, wf, a2[nb], 0, 0, 0);
      }
    }
    #pragma unroll
    for (int nb = 0; nb < 2; ++nb){
      const int n = n0 + nb*16 + kl;
      const float bias = bo[n];
      #pragma unroll
      for (int r = 0; r < 4; ++r)
        out[((size_t)(b*N_ + q0 + quad*4 + r))*256 + n] = a2[nb][r] + bias;
    }
  }
}

extern "C" void kernel_launch(void* const* d_in, const int* in_sizes, int n_in,
                              void* d_out, int out_size, void* d_ws, size_t ws_size,
                              hipStream_t stream)
{
  const float* query = (const float*)d_in[0];
  const float* key_  = (const float*)d_in[1];
  const float* value = (const float*)d_in[2];
  const float* adjm  = (const float*)d_in[3];
  const float* dist  = (const float*)d_in[4];
  // d_in[5] = edges_att (unused)
  const int*   mask  = (const int*)d_in[6];
  const float* Wq = (const float*)d_in[7];  const float* bq = (const float*)d_in[8];
  const float* Wk = (const float*)d_in[9];  const float* bk = (const float*)d_in[10];
  const float* Wv = (const float*)d_in[11]; const float* bv = (const float*)d_in[12];
  const float* Wo = (const float*)d_in[13]; const float* bo = (const float*)d_in[14];

  prep<<<5376, 256, 0, stream>>>(dist, adjm, mask, query, key_, value,
                                 Wq, Wk, Wv, Wo);
  qkv_gemm<<<1536, 256, 0, stream>>>(bq, bk, bv);
  attn_kernel<<<512, 512, 0, stream>>>(mask, bo, (float*)d_out);
}